// Round 6
// baseline (784.025 us; speedup 1.0000x reference)
//
#include <hip/hip_runtime.h>

#define NS 2048      // series = 256*8
#define T 4096
#define F 9
#define CH 44        // pooled-final rows per chunk: LDS 25.4 KB -> 6 blocks/CU
#define NCHUNK 12    // 11*44=484, last chunk nr=29

typedef float v2f __attribute__((ext_vector_type(2)));

// LDS: channel-major, time-contiguous, even strides
#define LXP 368      // x:  [9][368]   rows t_local in [0,366)
#define LUP 184      // p1: [16][184]  rows j in [0,182)
#define LWP 92       // p2: [32][92]   rows m in [0,90)
#define SM_X  0                  // 9*368  = 3312 floats
#define SM_P2 0                  // 32*92  = 2944 floats (overlaps X; X dead by then)
#define SM_P1 3312               // 16*184 = 2944 floats
#define SM_TOT (3312 + 2944 + 90)  // +90 slack for unguarded tail-strip reads; 25384 B

// Weight s_loads chunked behind `#pragma unroll 1` runtime loops (addr depends on
// loop var -> no LICM hoist -> no SGPR spill). Weight-block OUTER / strip INNER so
// weights load once per block-stage. Pooled pair packed in v2f -> v_pk_fma_f32.
__global__ __launch_bounds__(256) __attribute__((amdgpu_waves_per_eu(6, 8)))
void fused_cnn(
    const float* __restrict__ x,
    const float* __restrict__ w1, const float* __restrict__ b1,
    const float* __restrict__ w2, const float* __restrict__ b2,
    const float* __restrict__ w3, const float* __restrict__ b3,
    float* __restrict__ feat)
{
    __shared__ float sm[SM_TOT];
    const int tid  = threadIdx.x;
    const int lane = tid & 63;
    const int wid  = tid >> 6;          // wave id 0..3
    const int chunk = blockIdx.x;
    const int n     = blockIdx.y;
    const int r0 = chunk * CH;
    const int nr = min(CH, 513 - r0);   // 44, or 29 on last chunk
    const int nw = 2*nr + 2;            // p2 rows (90 / 60)
    const int nu = 4*nr + 6;            // p1 rows (182 / 122)
    const int nx = 8*nr + 14;           // x rows  (366 / 246)

    // ---- stage A: x window -> LDS transposed [f][t_local], zero-padded ----
    {
        const float* xs = x + (size_t)n * (T*F);
        const int gbase = (8*r0 - 14) * F;   // = t0*9
        const int tot = nx * F;
        for (int i = tid; i < tot; i += 256) {
            int tl = i / 9;
            int f  = i - tl*9;
            int gi = gbase + i;
            float v = (gi >= 0 && gi < T*F) ? xs[gi] : 0.f;
            sm[SM_X + f*LXP + tl] = v;
        }
    }
    __syncthreads();

    // ---- stage B: conv1(9->16,k3,p2)+relu+pool2 -> p1[c][j] ----
    {
        v2f acc[3][4];
        #pragma unroll
        for (int s = 0; s < 3; ++s)
            #pragma unroll
            for (int ic = 0; ic < 4; ++ic) acc[s][ic] = (v2f){0.f, 0.f};
        #pragma unroll 1
        for (int fb = 0; fb < 3; ++fb) {          // weight addr depends on fb
            float wv[3][4][3];
            #pragma unroll
            for (int fi = 0; fi < 3; ++fi)
                #pragma unroll
                for (int ic = 0; ic < 4; ++ic) {
                    const int cu = __builtin_amdgcn_readfirstlane(wid + 4*ic);
                    const float* wp = w1 + cu*27 + (fb*3 + fi)*3;
                    wv[fi][ic][0] = wp[0]; wv[fi][ic][1] = wp[1]; wv[fi][ic][2] = wp[2];
                }
            #pragma unroll
            for (int s = 0; s < 3; ++s) {
                if (s*64 < nu) {
                    const int j = s*64 + lane;
                    #pragma unroll
                    for (int fi = 0; fi < 3; ++fi) {
                        const float* xw = sm + SM_X + (fb*3 + fi)*LXP + 2*j;
                        float x0 = xw[0], x1 = xw[1], x2 = xw[2], x3 = xw[3];
                        v2f p01 = {x0, x1}, p12 = {x1, x2}, p23 = {x2, x3};
                        #pragma unroll
                        for (int ic = 0; ic < 4; ++ic) {
                            v2f w0s = {wv[fi][ic][0], wv[fi][ic][0]};
                            v2f w1s = {wv[fi][ic][1], wv[fi][ic][1]};
                            v2f w2s = {wv[fi][ic][2], wv[fi][ic][2]};
                            acc[s][ic] = __builtin_elementwise_fma(p01, w0s, acc[s][ic]);
                            acc[s][ic] = __builtin_elementwise_fma(p12, w1s, acc[s][ic]);
                            acc[s][ic] = __builtin_elementwise_fma(p23, w2s, acc[s][ic]);
                        }
                    }
                }
            }
        }
        #pragma unroll
        for (int s = 0; s < 3; ++s) {
            if (s*64 < nu) {
                const int j = s*64 + lane;
                const int u = 4*r0 - 6 + j;
                const bool uok = (j < nu) && (u >= 0) && (u < 2049);
                #pragma unroll
                for (int ic = 0; ic < 4; ++ic) {
                    const int cu = __builtin_amdgcn_readfirstlane(wid + 4*ic);
                    const float bc = b1[cu];
                    float res = uok ? fmaxf(fmaxf(acc[s][ic].x + bc, acc[s][ic].y + bc), 0.f) : 0.f;
                    if (j < nu) sm[SM_P1 + cu*LUP + j] = res;   // 0 = conv pad for stage C
                }
            }
        }
    }
    __syncthreads();

    // ---- stage C: conv2(16->32,k3,p2)+relu+pool2 -> p2[o][m] (overwrites X) ----
    {
        v2f acc[2][8];
        #pragma unroll
        for (int s = 0; s < 2; ++s)
            #pragma unroll
            for (int io = 0; io < 8; ++io) acc[s][io] = (v2f){0.f, 0.f};
        #pragma unroll 1
        for (int cb = 0; cb < 8; ++cb) {          // weight addr depends on cb
            float wv[2][8][3];
            #pragma unroll
            for (int cq = 0; cq < 2; ++cq)
                #pragma unroll
                for (int io = 0; io < 8; ++io) {
                    const int ou = __builtin_amdgcn_readfirstlane(wid + 4*io);
                    const float* wp = w2 + ou*48 + (cb*2 + cq)*3;
                    wv[cq][io][0] = wp[0]; wv[cq][io][1] = wp[1]; wv[cq][io][2] = wp[2];
                }
            #pragma unroll
            for (int s = 0; s < 2; ++s) {
                if (s*64 < nw) {
                    const int m = s*64 + lane;
                    #pragma unroll
                    for (int cq = 0; cq < 2; ++cq) {
                        const float* pw = sm + SM_P1 + (cb*2 + cq)*LUP + 2*m;
                        float p0 = pw[0], p1 = pw[1], p2v = pw[2], p3 = pw[3];
                        v2f q01 = {p0, p1}, q12 = {p1, p2v}, q23 = {p2v, p3};
                        #pragma unroll
                        for (int io = 0; io < 8; ++io) {
                            v2f w0s = {wv[cq][io][0], wv[cq][io][0]};
                            v2f w1s = {wv[cq][io][1], wv[cq][io][1]};
                            v2f w2s = {wv[cq][io][2], wv[cq][io][2]};
                            acc[s][io] = __builtin_elementwise_fma(q01, w0s, acc[s][io]);
                            acc[s][io] = __builtin_elementwise_fma(q12, w1s, acc[s][io]);
                            acc[s][io] = __builtin_elementwise_fma(q23, w2s, acc[s][io]);
                        }
                    }
                }
            }
        }
        __syncthreads();   // all P1 reads done before P2 (aliases X) is written
        #pragma unroll
        for (int s = 0; s < 2; ++s) {
            if (s*64 < nw) {
                const int m = s*64 + lane;
                const int w = 2*r0 - 2 + m;
                const bool wok = (m < nw) && (w >= 0) && (w < 1025);
                #pragma unroll
                for (int io = 0; io < 8; ++io) {
                    const int ou = __builtin_amdgcn_readfirstlane(wid + 4*io);
                    const float bo = b2[ou];
                    float res = wok ? fmaxf(fmaxf(acc[s][io].x + bo, acc[s][io].y + bo), 0.f) : 0.f;
                    if (m < nw) sm[SM_P2 + ou*LWP + m] = res;   // 0 = conv pad for stage D
                }
            }
        }
    }
    __syncthreads();

    // ---- stage D: conv3(32->16,k3,p2)+relu+pool2 -> sum over r -> feat ----
    {
        const bool rok = (lane < nr);
        v2f acc[4];
        #pragma unroll
        for (int io = 0; io < 4; ++io) acc[io] = (v2f){0.f, 0.f};
        #pragma unroll 1
        for (int cb = 0; cb < 8; ++cb) {          // weight addr depends on cb
            float wv[4][4][3];
            #pragma unroll
            for (int cq = 0; cq < 4; ++cq)
                #pragma unroll
                for (int io = 0; io < 4; ++io) {
                    const int ou = __builtin_amdgcn_readfirstlane(wid + 4*io);
                    const float* wp = w3 + ou*96 + (cb*4 + cq)*3;
                    wv[cq][io][0] = wp[0]; wv[cq][io][1] = wp[1]; wv[cq][io][2] = wp[2];
                }
            #pragma unroll
            for (int cq = 0; cq < 4; ++cq) {
                const float* pw = sm + SM_P2 + (cb*4 + cq)*LWP + 2*lane;
                float p0 = pw[0], p1 = pw[1], p2v = pw[2], p3 = pw[3];
                v2f q01 = {p0, p1}, q12 = {p1, p2v}, q23 = {p2v, p3};
                #pragma unroll
                for (int io = 0; io < 4; ++io) {
                    v2f w0s = {wv[cq][io][0], wv[cq][io][0]};
                    v2f w1s = {wv[cq][io][1], wv[cq][io][1]};
                    v2f w2s = {wv[cq][io][2], wv[cq][io][2]};
                    acc[io] = __builtin_elementwise_fma(q01, w0s, acc[io]);
                    acc[io] = __builtin_elementwise_fma(q12, w1s, acc[io]);
                    acc[io] = __builtin_elementwise_fma(q23, w2s, acc[io]);
                }
            }
        }
        #pragma unroll
        for (int io = 0; io < 4; ++io) {
            const int ou = __builtin_amdgcn_readfirstlane(wid + 4*io);
            const float bo = b3[ou];
            float v = fmaxf(fmaxf(acc[io].x + bo, acc[io].y + bo), 0.f);
            v = rok ? v : 0.f;
            #pragma unroll
            for (int off = 32; off >= 1; off >>= 1)
                v += __shfl_down(v, off, 64);
            if (lane == 0) atomicAdd(&feat[n*16 + ou], v);
        }
    }
}

// feat [2048,16] viewed as [256,128]; out[b][q] = max(feat[b,3q..3q+2]) / 513
__global__ void finalize_kernel(const float* __restrict__ feat, float* __restrict__ out) {
    int i = blockIdx.x * blockDim.x + threadIdx.x;
    if (i < 256*42) {
        int b = i / 42;
        int q = i - b*42;
        const float* f = feat + b*128 + q*3;
        out[i] = fmaxf(fmaxf(f[0], f[1]), f[2]) * (1.0f/513.0f);
    }
}

extern "C" void kernel_launch(void* const* d_in, const int* in_sizes, int n_in,
                              void* d_out, int out_size, void* d_ws, size_t ws_size,
                              hipStream_t stream) {
    const float* x  = (const float*)d_in[0];
    const float* w1 = (const float*)d_in[1];
    const float* b1 = (const float*)d_in[2];
    const float* w2 = (const float*)d_in[3];
    const float* b2 = (const float*)d_in[4];
    const float* w3 = (const float*)d_in[5];
    const float* b3 = (const float*)d_in[6];
    float* feat = (float*)d_ws;                       // 2048*16 floats = 128 KB
    hipMemsetAsync(feat, 0, NS*16*sizeof(float), stream);
    dim3 grid(NCHUNK, NS);
    fused_cnn<<<grid, 256, 0, stream>>>(x, w1, b1, w2, b2, w3, b3, feat);
    finalize_kernel<<<(256*42 + 255)/256, 256, 0, stream>>>(feat, (float*)d_out);
}